// Round 2
// baseline (324.182 us; speedup 1.0000x reference)
//
#include <hip/hip_runtime.h>
#include <math.h>

#define H 96
#define W 96
#define HW 9216
#define B 8
#define CIN 256
#define CM 64
#define NPOS (B*HW)    /* 73728 */
#define NBLK (NPOS/64) /* 1152 = 8 XCDs x 144 */

/* XCD swizzle: round-robin dispatch -> XCD g owns one batch image (2.25MB, fits 4MB L2).
   Applied to ALL per-position kernels so producer and consumer L2 match. */
__device__ __forceinline__ int xswiz(int n) { return (n & 7) * 144 + (n >> 3); }

typedef float  f32x4  __attribute__((ext_vector_type(4)));
typedef short  bf16x8 __attribute__((ext_vector_type(8)));

/* workspace layout (float offsets) — 33.8 MiB total */
#define OFF_WDBO  0         /* 9216 f = 18432 bf16: woff B-frags [kc18][nt2][lane][8] */
#define OFF_BNS   9216      /* 64 */
#define OFF_BNB   9280      /* 64 */
#define OFF_WDB1  9344      /* 8192 f = 16384 bf16: w1 B-frags [kc8][nt4][lane][8] */
#define OFF_WDB3  17536     /* 18432 f = 36864 bf16: wd B-frags [kc18][nt4][lane][8] */
#define OFF_WDB2  35968     /* 8192 f = 16384 bf16: w2 B-frags [kc2][nt16][lane][8] */
#define OFF_FCL   44160     /* 4718592: fcl[b][hw][64] channels-last fp32 */
#define OFF_OFFS  4762752   /* 1327104: offs[b][18][hw] */
#define OFF_VCL   6089856   /* 2359296 f = 4718592 bf16: vcl[pos][64] */

/* round-to-nearest-even fp32 -> bf16 (bit pattern in low 16) */
__device__ __forceinline__ unsigned bfbits(float f) {
  union { float f; unsigned u; } c;
  c.f = f;
  return (c.u + 0x7FFFu + ((c.u >> 16) & 1u)) >> 16;
}
__device__ __forceinline__ short f2bf(float f) { return (short)bfbits(f); }
__device__ __forceinline__ unsigned pack2(float lo, float hi) {
  return bfbits(lo) | (bfbits(hi) << 16);
}

/* k0: weight reformat. B-frag layout for mfma_f32_16x16x32_bf16:
   B[k][n], n = nt*16 + (lane&15), k = kc*32 + (lane>>4)*8 + j  (j=0..7 contiguous) */
__global__ __launch_bounds__(256) void k0_prep(
    const float* __restrict__ w1, const float* __restrict__ woff,
    const float* __restrict__ wd, const float* __restrict__ w2,
    const float* __restrict__ gamma, const float* __restrict__ beta,
    const float* __restrict__ rmean, const float* __restrict__ rvar,
    float* __restrict__ ws) {
  int i = blockIdx.x * 256 + threadIdx.x;
  if (i < 18432) {                      /* wdbo: K=(ks*64+c)(576), N=o(18,pad32) from woff[o][c][ks] */
    int j = i;
    int j8 = j & 7, lane = (j >> 3) & 63, nt = (j >> 9) & 1, kc = j >> 10;
    int n = nt * 16 + (lane & 15);
    int c = (kc & 1) * 32 + ((lane >> 4) & 3) * 8 + j8;
    int ks = kc >> 1;
    ((short*)(ws + OFF_WDBO))[j] = (n < 18) ? f2bf(woff[(n * 64 + c) * 9 + ks]) : (short)0;
  } else if (i < 18496) {               /* BN folding */
    int o = i - 18432;
    float inv = gamma[o] / sqrtf(rvar[o] + 1e-5f);
    ws[OFF_BNS + o] = inv;
    ws[OFF_BNB + o] = beta[o] - rmean[o] * inv;
  } else if (i < 34880) {               /* wdb1: K=c(256), N=o(64) from w1[o][c] */
    int j = i - 18496;
    int j8 = j & 7, lane = (j >> 3) & 63, nt = (j >> 9) & 3, kc = j >> 11;
    int n = nt * 16 + (lane & 15);
    int c = kc * 32 + ((lane >> 4) & 3) * 8 + j8;
    ((short*)(ws + OFF_WDB1))[j] = f2bf(w1[n * 256 + c]);
  } else if (i < 71744) {               /* wdb3: K=(kstep*64+c)(576), N=o from wd[o][c][kstep] */
    int j = i - 34880;
    int j8 = j & 7, lane = (j >> 3) & 63, nt = (j >> 9) & 3, kc = j >> 11;
    int n = nt * 16 + (lane & 15);
    int c = (kc & 1) * 32 + ((lane >> 4) & 3) * 8 + j8;
    int ks = kc >> 1;
    ((short*)(ws + OFF_WDB3))[j] = f2bf(wd[(n * 64 + c) * 9 + ks]);
  } else if (i < 88128) {               /* wdb2: K=c(64), N=o(256) from w2[o][c] */
    int j = i - 71744;
    int j8 = j & 7, lane = (j >> 3) & 63, nt = (j >> 9) & 15, kc = j >> 13;
    int n = nt * 16 + (lane & 15);
    int c = kc * 32 + ((lane >> 4) & 3) * 8 + j8;
    ((short*)(ws + OFF_WDB2))[j] = f2bf(w2[n * 64 + c]);
  }
}

/* k1: pwconv1 via MFMA. M=64 pos, N=64 o, K=256. A-frags built directly in
   registers from x (no LDS in main loop). Emits fcl [pos][64] only. */
__global__ __launch_bounds__(256) void k1_pw1(
    const float* __restrict__ x, const short* __restrict__ wdb1,
    const float* __restrict__ b1, float* __restrict__ fcl) {
  __shared__ float sA[64 * 66];  /* epilogue transpose only */
  int t = threadIdx.x;
  int lane = t & 63;
  int qq = __builtin_amdgcn_readfirstlane(t >> 6);
  int quad = lane >> 4, l15 = lane & 15;
  int gpos0 = xswiz(blockIdx.x) * 64;
  int b = gpos0 / HW, hw0 = gpos0 - b * HW;
  /* lane's A-row position = gpos0 + qq*16 + l15; channels quad*8 + j */
  const float* xp = x + (size_t)b * CIN * HW + (size_t)(quad * 8) * HW + hw0 + qq * 16 + l15;
  f32x4 acc[4];
#pragma unroll
  for (int nt = 0; nt < 4; nt++) acc[nt] = (f32x4){0.f, 0.f, 0.f, 0.f};

#pragma unroll 2
  for (int kc = 0; kc < 8; kc++) {
    float v[8];
#pragma unroll
    for (int j = 0; j < 8; j++) v[j] = xp[(size_t)(kc * 32 + j) * HW];
    union { unsigned u[4]; bf16x8 f; } af;
    af.u[0] = pack2(v[0], v[1]); af.u[1] = pack2(v[2], v[3]);
    af.u[2] = pack2(v[4], v[5]); af.u[3] = pack2(v[6], v[7]);
#pragma unroll
    for (int nt = 0; nt < 4; nt++) {
      bf16x8 bf = ((const bf16x8*)wdb1)[(kc * 4 + nt) * 64 + lane];
      acc[nt] = __builtin_amdgcn_mfma_f32_16x16x32_bf16(af.f, bf, acc[nt], 0, 0, 0);
    }
  }
  /* epilogue: D[m=qq*16+quad*4+reg][o=nt*16+l15] + bias -> LDS -> fcl rows */
#pragma unroll
  for (int nt = 0; nt < 4; nt++) {
    int o = nt * 16 + l15;
#pragma unroll
    for (int reg = 0; reg < 4; reg++) {
      int m = qq * 16 + quad * 4 + reg;
      sA[m * 66 + o] = acc[nt][reg] + b1[o];
    }
  }
  __syncthreads();
  for (int rr = t; rr < 4096; rr += 256) {
    int p2 = rr >> 6, o2 = rr & 63;
    fcl[(size_t)(gpos0 + p2) * 64 + o2] = sA[p2 * 66 + o2];
  }
}

/* k2: offset conv 64->18 as MFMA im2col from fcl. M=64 pos, N=32 (18 used),
   K=576 (9 taps x 64c). A-frags in registers; acc fp32. */
__global__ __launch_bounds__(256) void k2_off(
    const float* __restrict__ fcl, const short* __restrict__ wdbo,
    const float* __restrict__ boff, float* __restrict__ offs) {
  __shared__ float sP[64 * 34];
  int t = threadIdx.x;
  int lane = t & 63;
  int qq = __builtin_amdgcn_readfirstlane(t >> 6);
  int quad = lane >> 4, l15 = lane & 15;
  int gpos0 = xswiz(blockIdx.x) * 64;
  int b = gpos0 / HW, hw0 = gpos0 - b * HW;
  int m = qq * 16 + l15;                 /* this lane's A-row */
  int hw = hw0 + m, i = hw / W, j = hw - i * W;
  f32x4 acc[2];
  acc[0] = (f32x4){0.f, 0.f, 0.f, 0.f};
  acc[1] = (f32x4){0.f, 0.f, 0.f, 0.f};

#pragma unroll 1
  for (int ks = 0; ks < 9; ks++) {
    int dy = ks / 3 - 1, dx = ks % 3 - 1;
    bool ok = ((unsigned)(i + dy) < (unsigned)H) && ((unsigned)(j + dx) < (unsigned)W);
    int spos = gpos0 + m + (ok ? dy * W + dx : 0);   /* clamp: never OOB, garbage masked */
    const float* src = fcl + (size_t)spos * 64 + quad * 8;
#pragma unroll
    for (int ch = 0; ch < 2; ch++) {
      f32x4 va = *(const f32x4*)(src + ch * 32);
      f32x4 vb = *(const f32x4*)(src + ch * 32 + 4);
      if (!ok) { va = (f32x4){0.f,0.f,0.f,0.f}; vb = (f32x4){0.f,0.f,0.f,0.f}; }
      union { unsigned u[4]; bf16x8 f; } af;
      af.u[0] = pack2(va[0], va[1]); af.u[1] = pack2(va[2], va[3]);
      af.u[2] = pack2(vb[0], vb[1]); af.u[3] = pack2(vb[2], vb[3]);
      int kc = ks * 2 + ch;
#pragma unroll
      for (int nt = 0; nt < 2; nt++) {
        bf16x8 bf = ((const bf16x8*)wdbo)[(kc * 2 + nt) * 64 + lane];
        acc[nt] = __builtin_amdgcn_mfma_f32_16x16x32_bf16(af.f, bf, acc[nt], 0, 0, 0);
      }
    }
  }
  /* epilogue: D[m][o] -> LDS transpose -> offs[b][o][hw] */
#pragma unroll
  for (int nt = 0; nt < 2; nt++)
#pragma unroll
    for (int reg = 0; reg < 4; reg++) {
      int mm = qq * 16 + quad * 4 + reg;
      sP[mm * 34 + nt * 16 + l15] = acc[nt][reg];
    }
  __syncthreads();
  for (int rr = t; rr < 18 * 64; rr += 256) {
    int o = rr >> 6, p = rr & 63;
    offs[((size_t)b * 18 + o) * HW + hw0 + p] = sP[p * 34 + o] + boff[o];
  }
}

/* k3: deformable conv + BN via MFMA. M=64 pos, N=64 o, K=576.
   Gathers go DIRECTLY into per-lane A-fragments (2 x f32x4 per tap), weighted
   in fp32, packed to bf16 in registers. Zero LDS in the main loop. */
__global__ __launch_bounds__(256) void k3_deform(
    const float* __restrict__ fcl, const float* __restrict__ offs,
    const short* __restrict__ wdb3, const float* __restrict__ bd,
    const float* __restrict__ bns, const float* __restrict__ bnb,
    short* __restrict__ vclb) {
  __shared__ int2 tiw[4][576];                  /* .x = byte off, .y = weight bits */
  __shared__ __align__(16) short sEp[64 * 72];  /* epilogue staging, pitch 144B */
  int t = threadIdx.x;
  int lane = t & 63;
  int qq = __builtin_amdgcn_readfirstlane(t >> 6);
  int quad = lane >> 4, l15 = lane & 15;
  int mrow = qq * 16 + l15;
  int gpos0 = xswiz(blockIdx.x) * 64;
  int b = gpos0 / HW, hw0 = gpos0 - b * HW;
  int hw = hw0 + lane;
  int i = hw / W, j = hw - i * W;
  const float* ob = offs + (size_t)b * 18 * HW + hw;

  /* tap precompute: wave qq handles k = qq, qq+4, ... (lane = pos) */
  for (int k = qq; k < 9; k += 4) {
    float dy = ob[(2 * k + 0) * HW];
    float dx = ob[(2 * k + 1) * HW];
    float py = (float)(i + k / 3 - 1) + dy;
    float px = (float)(j + k % 3 - 1) + dx;
    float y0f = floorf(py), x0f = floorf(px);
    int y0 = (int)y0f, x0 = (int)x0f;
    float fy = py - y0f, fx = px - x0f;
    float w00 = (1.f - fy) * (1.f - fx), w01 = (1.f - fy) * fx;
    float w10 = fy * (1.f - fx), w11 = fy * fx;
    bool vy0 = (y0 >= 0) && (y0 < H), vy1 = (y0 + 1 >= 0) && (y0 + 1 < H);
    bool vx0 = (x0 >= 0) && (x0 < W), vx1 = (x0 + 1 >= 0) && (x0 + 1 < W);
    if (!(vy0 && vx0)) w00 = 0.f;
    if (!(vy0 && vx1)) w01 = 0.f;
    if (!(vy1 && vx0)) w10 = 0.f;
    if (!(vy1 && vx1)) w11 = 0.f;
    int yi0 = min(max(y0, 0), H - 1), yi1 = min(max(y0 + 1, 0), H - 1);
    int xi0 = min(max(x0, 0), W - 1), xi1 = min(max(x0 + 1, 0), W - 1);
    int e = k * 64 + lane;
    tiw[0][e] = make_int2((yi0 * W + xi0) * 256, __float_as_int(w00));
    tiw[1][e] = make_int2((yi0 * W + xi1) * 256, __float_as_int(w01));
    tiw[2][e] = make_int2((yi1 * W + xi0) * 256, __float_as_int(w10));
    tiw[3][e] = make_int2((yi1 * W + xi1) * 256, __float_as_int(w11));
  }
  __syncthreads();

  const char* fb = (const char*)fcl + (size_t)b * HW * 256;
  f32x4 acc[4];
#pragma unroll
  for (int nt = 0; nt < 4; nt++) acc[nt] = (f32x4){0.f, 0.f, 0.f, 0.f};

#pragma unroll 1
  for (int ks = 0; ks < 9; ks++) {
    int e = ks * 64 + mrow;
    int2 t0 = tiw[0][e], t1 = tiw[1][e], t2 = tiw[2][e], t3 = tiw[3][e];
    float w0 = __int_as_float(t0.y), w1 = __int_as_float(t1.y);
    float w2 = __int_as_float(t2.y), w3 = __int_as_float(t3.y);
#pragma unroll
    for (int ch = 0; ch < 2; ch++) {
      int bo = ch * 128 + quad * 32;
      f32x4 va0 = *(const f32x4*)(fb + (t0.x + bo));
      f32x4 va1 = *(const f32x4*)(fb + (t1.x + bo));
      f32x4 va2 = *(const f32x4*)(fb + (t2.x + bo));
      f32x4 va3 = *(const f32x4*)(fb + (t3.x + bo));
      f32x4 vb0 = *(const f32x4*)(fb + (t0.x + bo + 16));
      f32x4 vb1 = *(const f32x4*)(fb + (t1.x + bo + 16));
      f32x4 vb2 = *(const f32x4*)(fb + (t2.x + bo + 16));
      f32x4 vb3 = *(const f32x4*)(fb + (t3.x + bo + 16));
      f32x4 slo = w0 * va0 + w1 * va1 + w2 * va2 + w3 * va3;
      f32x4 shi = w0 * vb0 + w1 * vb1 + w2 * vb2 + w3 * vb3;
      union { unsigned u[4]; bf16x8 f; } af;
      af.u[0] = pack2(slo[0], slo[1]); af.u[1] = pack2(slo[2], slo[3]);
      af.u[2] = pack2(shi[0], shi[1]); af.u[3] = pack2(shi[2], shi[3]);
      int kc = ks * 2 + ch;
#pragma unroll
      for (int nt = 0; nt < 4; nt++) {
        bf16x8 bf = ((const bf16x8*)wdb3)[(kc * 4 + nt) * 64 + lane];
        acc[nt] = __builtin_amdgcn_mfma_f32_16x16x32_bf16(af.f, bf, acc[nt], 0, 0, 0);
      }
    }
  }
  /* epilogue: bias + BN, bf16 stage to LDS (wave-private rows), write vcl bf16 */
#pragma unroll
  for (int nt = 0; nt < 4; nt++) {
    int o = nt * 16 + l15;
    float sc = bns[o], sb = bnb[o], bb = bd[o];
#pragma unroll
    for (int reg = 0; reg < 4; reg++) {
      int m = qq * 16 + quad * 4 + reg;
      sEp[m * 72 + o] = f2bf((acc[nt][reg] + bb) * sc + sb);
    }
  }
  __syncthreads();
  for (int rr = t; rr < 2048; rr += 256) {
    int p = rr >> 5, cc = rr & 31;
    ((unsigned*)vclb)[(size_t)(gpos0 + p) * 32 + cc] = ((const unsigned*)sEp)[p * 36 + cc];
  }
}

/* k4: pwconv2 via MFMA (M=64 pos, N=256 o, K=64) + sigmoid gate.
   A-frags loaded directly from bf16 vcl (no LDS staging, no cvt). */
__global__ __launch_bounds__(256) void k4_pw2(
    const float* __restrict__ x, const short* __restrict__ vclb,
    const short* __restrict__ wdb2, const float* __restrict__ b2,
    float* __restrict__ out) {
  __shared__ float sA[64 * 66];
  int t = threadIdx.x;
  int lane = t & 63;
  int qq = __builtin_amdgcn_readfirstlane(t >> 6);
  int quad = lane >> 4, l15 = lane & 15;
  int mrow = qq * 16 + l15;
  int gpos0 = xswiz(blockIdx.x) * 64;
  int b = gpos0 / HW, hw0 = gpos0 - b * HW;

  const bf16x8* ap = (const bf16x8*)(vclb + (size_t)(gpos0 + mrow) * 64);
  bf16x8 af0 = ap[quad];
  bf16x8 af1 = ap[4 + quad];

  f32x4 acc[16];
#pragma unroll
  for (int nt = 0; nt < 16; nt++) acc[nt] = (f32x4){0.f, 0.f, 0.f, 0.f};
#pragma unroll
  for (int nt = 0; nt < 16; nt++) {
    bf16x8 bf0 = ((const bf16x8*)wdb2)[(0 * 16 + nt) * 64 + lane];
    bf16x8 bf1 = ((const bf16x8*)wdb2)[(1 * 16 + nt) * 64 + lane];
    acc[nt] = __builtin_amdgcn_mfma_f32_16x16x32_bf16(af0, bf0, acc[nt], 0, 0, 0);
    acc[nt] = __builtin_amdgcn_mfma_f32_16x16x32_bf16(af1, bf1, acc[nt], 0, 0, 0);
  }
  /* epilogue in 4 chunks of 64 out-channels through LDS */
  for (int nc = 0; nc < 4; nc++) {
    __syncthreads();
#pragma unroll
    for (int nt2 = 0; nt2 < 4; nt2++) {
      int nt = nc * 4 + nt2;
      int o1 = nt2 * 16 + l15;
#pragma unroll
      for (int reg = 0; reg < 4; reg++) {
        int m = qq * 16 + quad * 4 + reg;
        sA[m * 66 + o1] = acc[nt][reg] + b2[nc * 64 + nt2 * 16 + l15];
      }
    }
    __syncthreads();
    for (int rr = t; rr < 4096; rr += 256) {
      int o1 = rr >> 6, p = rr & 63;
      int o = nc * 64 + o1;
      float wv = sA[p * 66 + o1];
      float sg = 1.f / (1.f + __expf(-wv));
      size_t gi = ((size_t)b * CIN + o) * HW + hw0 + p;
      out[gi] = x[gi] * sg;
    }
  }
}

extern "C" void kernel_launch(void* const* d_in, const int* in_sizes, int n_in,
                              void* d_out, int out_size, void* d_ws, size_t ws_size,
                              hipStream_t stream) {
  const float* x     = (const float*)d_in[0];
  const float* w1    = (const float*)d_in[1];
  const float* b1    = (const float*)d_in[2];
  const float* woff  = (const float*)d_in[3];
  const float* boff  = (const float*)d_in[4];
  const float* wd    = (const float*)d_in[5];
  const float* bd    = (const float*)d_in[6];
  const float* gamma = (const float*)d_in[7];
  const float* beta  = (const float*)d_in[8];
  const float* rmean = (const float*)d_in[9];
  const float* rvar  = (const float*)d_in[10];
  const float* w2    = (const float*)d_in[11];
  const float* b2    = (const float*)d_in[12];
  float* out = (float*)d_out;
  float* ws  = (float*)d_ws;

  dim3 blk(256);
  k0_prep<<<dim3(345), blk, 0, stream>>>(w1, woff, wd, w2, gamma, beta, rmean, rvar, ws);
  k1_pw1<<<dim3(NBLK), blk, 0, stream>>>(x, (const short*)(ws + OFF_WDB1), b1, ws + OFF_FCL);
  k2_off<<<dim3(NBLK), blk, 0, stream>>>(ws + OFF_FCL, (const short*)(ws + OFF_WDBO),
                                         boff, ws + OFF_OFFS);
  k3_deform<<<dim3(NBLK), blk, 0, stream>>>(ws + OFF_FCL, ws + OFF_OFFS,
                                            (const short*)(ws + OFF_WDB3), bd,
                                            ws + OFF_BNS, ws + OFF_BNB,
                                            (short*)(ws + OFF_VCL));
  k4_pw2<<<dim3(NBLK), blk, 0, stream>>>(x, (const short*)(ws + OFF_VCL),
                                         (const short*)(ws + OFF_WDB2), b2, out);
}

// Round 3
// 292.013 us; speedup vs baseline: 1.1102x; 1.1102x over previous
//
#include <hip/hip_runtime.h>
#include <math.h>

#define H 96
#define W 96
#define HW 9216
#define B 8
#define CIN 256
#define CM 64
#define NPOS (B*HW)    /* 73728 */
#define NBLK (NPOS/64) /* 1152 = 8 XCDs x 144 */

/* XCD swizzle: round-robin dispatch -> XCD g owns one batch image (2.25MB, fits 4MB L2).
   Applied to ALL per-position kernels so producer and consumer L2 match. */
__device__ __forceinline__ int xswiz(int n) { return (n & 7) * 144 + (n >> 3); }

typedef float  f32x4  __attribute__((ext_vector_type(4)));
typedef short  bf16x8 __attribute__((ext_vector_type(8)));

/* workspace layout (float offsets) */
#define OFF_WDBO  0         /* 9216 f = 18432 bf16: woff B-frags [kc18][nt2][lane][8] */
#define OFF_BNS   9216      /* 64 */
#define OFF_BNB   9280      /* 64 */
#define OFF_WDB1  9344      /* 8192 f = 16384 bf16: w1 B-frags [kc8][nt4][lane][8] */
#define OFF_WDB3  17536     /* 18432 f = 36864 bf16: wd B-frags [kc18][nt4][lane][8] */
#define OFF_WDB2  35968     /* 8192 f = 16384 bf16: w2 B-frags [kc2][nt16][lane][8] */
#define OFF_FCL   44160     /* 4718592: fcl[b][hw][64] channels-last fp32 */
#define OFF_OFFS  4762752   /* 1327104: offs[b][18][hw] */
#define OFF_VCL   6089856   /* 2359296 f = 4718592 bf16: vcl[pos][64] */

/* round-to-nearest-even fp32 -> bf16 (bit pattern in low 16) */
__device__ __forceinline__ unsigned bfbits(float f) {
  union { float f; unsigned u; } c;
  c.f = f;
  return (c.u + 0x7FFFu + ((c.u >> 16) & 1u)) >> 16;
}
__device__ __forceinline__ short f2bf(float f) { return (short)bfbits(f); }
__device__ __forceinline__ unsigned pack2(float lo, float hi) {
  return bfbits(lo) | (bfbits(hi) << 16);
}

/* k0: weight reformat. B-frag layout for mfma_f32_16x16x32_bf16:
   B[k][n], n = nt*16 + (lane&15), k = kc*32 + (lane>>4)*8 + j  (j=0..7 contiguous) */
__global__ __launch_bounds__(256) void k0_prep(
    const float* __restrict__ w1, const float* __restrict__ woff,
    const float* __restrict__ wd, const float* __restrict__ w2,
    const float* __restrict__ gamma, const float* __restrict__ beta,
    const float* __restrict__ rmean, const float* __restrict__ rvar,
    float* __restrict__ ws) {
  int i = blockIdx.x * 256 + threadIdx.x;
  if (i < 18432) {                      /* wdbo: K=(ks*64+c)(576), N=o(18,pad32) */
    int j = i;
    int j8 = j & 7, lane = (j >> 3) & 63, nt = (j >> 9) & 1, kc = j >> 10;
    int n = nt * 16 + (lane & 15);
    int c = (kc & 1) * 32 + ((lane >> 4) & 3) * 8 + j8;
    int ks = kc >> 1;
    ((short*)(ws + OFF_WDBO))[j] = (n < 18) ? f2bf(woff[(n * 64 + c) * 9 + ks]) : (short)0;
  } else if (i < 18496) {               /* BN folding */
    int o = i - 18432;
    float inv = gamma[o] / sqrtf(rvar[o] + 1e-5f);
    ws[OFF_BNS + o] = inv;
    ws[OFF_BNB + o] = beta[o] - rmean[o] * inv;
  } else if (i < 34880) {               /* wdb1: K=c(256), N=o(64) from w1[o][c] */
    int j = i - 18496;
    int j8 = j & 7, lane = (j >> 3) & 63, nt = (j >> 9) & 3, kc = j >> 11;
    int n = nt * 16 + (lane & 15);
    int c = kc * 32 + ((lane >> 4) & 3) * 8 + j8;
    ((short*)(ws + OFF_WDB1))[j] = f2bf(w1[n * 256 + c]);
  } else if (i < 71744) {               /* wdb3: K=(kstep*64+c)(576), N=o from wd[o][c][kstep] */
    int j = i - 34880;
    int j8 = j & 7, lane = (j >> 3) & 63, nt = (j >> 9) & 3, kc = j >> 11;
    int n = nt * 16 + (lane & 15);
    int c = (kc & 1) * 32 + ((lane >> 4) & 3) * 8 + j8;
    int ks = kc >> 1;
    ((short*)(ws + OFF_WDB3))[j] = f2bf(wd[(n * 64 + c) * 9 + ks]);
  } else if (i < 88128) {               /* wdb2: K=c(64), N=o(256) from w2[o][c] */
    int j = i - 71744;
    int j8 = j & 7, lane = (j >> 3) & 63, nt = (j >> 9) & 15, kc = j >> 13;
    int n = nt * 16 + (lane & 15);
    int c = kc * 32 + ((lane >> 4) & 3) * 8 + j8;
    ((short*)(ws + OFF_WDB2))[j] = f2bf(w2[n * 64 + c]);
  }
}

/* k1: pwconv1 via MFMA. M=64 pos, N=64 o, K=256. ALL 64 x-loads issued up-front
   (max MLP against ~900cy HBM latency), consumed kc-by-kc with progressive vmcnt. */
__global__ __launch_bounds__(256) void k1_pw1(
    const float* __restrict__ x, const short* __restrict__ wdb1,
    const float* __restrict__ b1, float* __restrict__ fcl) {
  __shared__ float sA[64 * 66];  /* epilogue transpose only */
  int t = threadIdx.x;
  int lane = t & 63;
  int qq = __builtin_amdgcn_readfirstlane(t >> 6);
  int quad = lane >> 4, l15 = lane & 15;
  int gpos0 = xswiz(blockIdx.x) * 64;
  int b = gpos0 / HW, hw0 = gpos0 - b * HW;
  const float* xp = x + (size_t)b * CIN * HW + (size_t)(quad * 8) * HW + hw0 + qq * 16 + l15;

  float v[8][8];
#pragma unroll
  for (int kc = 0; kc < 8; kc++)
#pragma unroll
    for (int jj = 0; jj < 8; jj++)
      v[kc][jj] = xp[(size_t)(kc * 32 + jj) * HW];

  f32x4 acc[4];
#pragma unroll
  for (int nt = 0; nt < 4; nt++) acc[nt] = (f32x4){0.f, 0.f, 0.f, 0.f};
#pragma unroll
  for (int kc = 0; kc < 8; kc++) {
    union { unsigned u[4]; bf16x8 f; } af;
    af.u[0] = pack2(v[kc][0], v[kc][1]); af.u[1] = pack2(v[kc][2], v[kc][3]);
    af.u[2] = pack2(v[kc][4], v[kc][5]); af.u[3] = pack2(v[kc][6], v[kc][7]);
#pragma unroll
    for (int nt = 0; nt < 4; nt++) {
      bf16x8 bf = ((const bf16x8*)wdb1)[(kc * 4 + nt) * 64 + lane];
      acc[nt] = __builtin_amdgcn_mfma_f32_16x16x32_bf16(af.f, bf, acc[nt], 0, 0, 0);
    }
  }
  /* epilogue: D[m=qq*16+quad*4+reg][o=nt*16+l15] + bias -> LDS -> fcl rows */
#pragma unroll
  for (int nt = 0; nt < 4; nt++) {
    int o = nt * 16 + l15;
#pragma unroll
    for (int reg = 0; reg < 4; reg++) {
      int m = qq * 16 + quad * 4 + reg;
      sA[m * 66 + o] = acc[nt][reg] + b1[o];
    }
  }
  __syncthreads();
  for (int rr = t; rr < 4096; rr += 256) {
    int p2 = rr >> 6, o2 = rr & 63;
    fcl[(size_t)(gpos0 + p2) * 64 + o2] = sA[p2 * 66 + o2];
  }
}

/* k2: offset conv 64->18 as MFMA im2col from fcl. M=64 pos, N=32 (18 used),
   K=576. Depth-1 prefetch: tap ks+1's 4 f32x4 loads issued before ks's MFMAs. */
__global__ __launch_bounds__(256) void k2_off(
    const float* __restrict__ fcl, const short* __restrict__ wdbo,
    const float* __restrict__ boff, float* __restrict__ offs) {
  __shared__ float sP[64 * 34];
  int t = threadIdx.x;
  int lane = t & 63;
  int qq = __builtin_amdgcn_readfirstlane(t >> 6);
  int quad = lane >> 4, l15 = lane & 15;
  int gpos0 = xswiz(blockIdx.x) * 64;
  int b = gpos0 / HW, hw0 = gpos0 - b * HW;
  int m = qq * 16 + l15;                 /* this lane's A-row */
  int hw = hw0 + m, i = hw / W, j = hw - i * W;
  const float* base = fcl + (size_t)(gpos0 + m) * 64 + quad * 8;

  f32x4 acc[2];
  acc[0] = (f32x4){0.f, 0.f, 0.f, 0.f};
  acc[1] = (f32x4){0.f, 0.f, 0.f, 0.f};

  f32x4 va0, vb0, va1, vb1;
  bool okc;
  { /* tap 0: dy=-1,dx=-1 */
    okc = (i >= 1) && (j >= 1);
    const float* s = base + (okc ? (-W - 1) * 64 : 0);
    va0 = *(const f32x4*)(s);      vb0 = *(const f32x4*)(s + 4);
    va1 = *(const f32x4*)(s + 32); vb1 = *(const f32x4*)(s + 36);
  }
#pragma unroll
  for (int ks = 0; ks < 9; ks++) {
    f32x4 z = (f32x4){0.f, 0.f, 0.f, 0.f};
    f32x4 a0 = okc ? va0 : z, c0 = okc ? vb0 : z;
    f32x4 a1 = okc ? va1 : z, c1 = okc ? vb1 : z;
    union { unsigned u[4]; bf16x8 f; } f0, f1;
    f0.u[0] = pack2(a0[0], a0[1]); f0.u[1] = pack2(a0[2], a0[3]);
    f0.u[2] = pack2(c0[0], c0[1]); f0.u[3] = pack2(c0[2], c0[3]);
    f1.u[0] = pack2(a1[0], a1[1]); f1.u[1] = pack2(a1[2], a1[3]);
    f1.u[2] = pack2(c1[0], c1[1]); f1.u[3] = pack2(c1[2], c1[3]);
    if (ks < 8) { /* prefetch next tap */
      int kn = ks + 1, dy = kn / 3 - 1, dx = kn % 3 - 1;
      okc = ((unsigned)(i + dy) < (unsigned)H) && ((unsigned)(j + dx) < (unsigned)W);
      const float* s = base + (okc ? (dy * W + dx) * 64 : 0);
      va0 = *(const f32x4*)(s);      vb0 = *(const f32x4*)(s + 4);
      va1 = *(const f32x4*)(s + 32); vb1 = *(const f32x4*)(s + 36);
    }
    bf16x8 bf00 = ((const bf16x8*)wdbo)[((ks * 2 + 0) * 2 + 0) * 64 + lane];
    bf16x8 bf01 = ((const bf16x8*)wdbo)[((ks * 2 + 0) * 2 + 1) * 64 + lane];
    bf16x8 bf10 = ((const bf16x8*)wdbo)[((ks * 2 + 1) * 2 + 0) * 64 + lane];
    bf16x8 bf11 = ((const bf16x8*)wdbo)[((ks * 2 + 1) * 2 + 1) * 64 + lane];
    acc[0] = __builtin_amdgcn_mfma_f32_16x16x32_bf16(f0.f, bf00, acc[0], 0, 0, 0);
    acc[1] = __builtin_amdgcn_mfma_f32_16x16x32_bf16(f0.f, bf01, acc[1], 0, 0, 0);
    acc[0] = __builtin_amdgcn_mfma_f32_16x16x32_bf16(f1.f, bf10, acc[0], 0, 0, 0);
    acc[1] = __builtin_amdgcn_mfma_f32_16x16x32_bf16(f1.f, bf11, acc[1], 0, 0, 0);
  }
  /* epilogue: D[m][o] -> LDS transpose -> offs[b][o][hw] */
#pragma unroll
  for (int nt = 0; nt < 2; nt++)
#pragma unroll
    for (int reg = 0; reg < 4; reg++) {
      int mm = qq * 16 + quad * 4 + reg;
      sP[mm * 34 + nt * 16 + l15] = acc[nt][reg];
    }
  __syncthreads();
  for (int rr = t; rr < 18 * 64; rr += 256) {
    int o = rr >> 6, p = rr & 63;
    offs[((size_t)b * 18 + o) * HW + hw0 + p] = sP[p * 34 + o] + boff[o];
  }
}

/* k3: deformable conv + BN via MFMA. M=64 pos, N=64 o, K=576 (9 ks x 64c).
   Coalesced gathers (lane = channel-pair, 2 positions per half-wave) into a
   ring of 8 register slots; (ks,pp)-granular software pipeline: consume slot
   (weight+pack+ds_write to ping-pong LDS A-tile) then re-issue it with ks+1's
   4 tap loads -> gathers have a full ks phase to land; 32 loads in flight. */
__global__ __launch_bounds__(256, 3) void k3_deform(
    const float* __restrict__ fcl, const float* __restrict__ offs,
    const short* __restrict__ wdb3, const float* __restrict__ bd,
    const float* __restrict__ bns, const float* __restrict__ bnb,
    short* __restrict__ vclb) {
  __shared__ __align__(16) short sAb[2][64 * 72];  /* ping-pong bf16 A-tiles */
  __shared__ __align__(16) int2 tiw[576][4];       /* per (ks*64+pos): 4 taps {byteoff, wbits} */
  int t = threadIdx.x;
  int lane = t & 63;
  int qq = __builtin_amdgcn_readfirstlane(t >> 6);
  int quad = lane >> 4, l15 = lane & 15;
  int mrow = qq * 16 + l15;
  int gpos0 = xswiz(blockIdx.x) * 64;
  int b = gpos0 / HW, hw0 = gpos0 - b * HW;
  int hw = hw0 + lane;
  int i = hw / W, j = hw - i * W;
  const float* ob = offs + (size_t)b * 18 * HW + hw;

  /* tap precompute: wave qq handles k = qq, qq+4, ... (lane = pos) */
  for (int k = qq; k < 9; k += 4) {
    float dy = ob[(2 * k + 0) * HW];
    float dx = ob[(2 * k + 1) * HW];
    float py = (float)(i + k / 3 - 1) + dy;
    float px = (float)(j + k % 3 - 1) + dx;
    float y0f = floorf(py), x0f = floorf(px);
    int y0 = (int)y0f, x0 = (int)x0f;
    float fy = py - y0f, fx = px - x0f;
    float w00 = (1.f - fy) * (1.f - fx), w01 = (1.f - fy) * fx;
    float w10 = fy * (1.f - fx), w11 = fy * fx;
    bool vy0 = (y0 >= 0) && (y0 < H), vy1 = (y0 + 1 >= 0) && (y0 + 1 < H);
    bool vx0 = (x0 >= 0) && (x0 < W), vx1 = (x0 + 1 >= 0) && (x0 + 1 < W);
    if (!(vy0 && vx0)) w00 = 0.f;
    if (!(vy0 && vx1)) w01 = 0.f;
    if (!(vy1 && vx0)) w10 = 0.f;
    if (!(vy1 && vx1)) w11 = 0.f;
    int yi0 = min(max(y0, 0), H - 1), yi1 = min(max(y0 + 1, 0), H - 1);
    int xi0 = min(max(x0, 0), W - 1), xi1 = min(max(x0 + 1, 0), W - 1);
    int e = k * 64 + lane;
    tiw[e][0] = make_int2((yi0 * W + xi0) * 256, __float_as_int(w00));
    tiw[e][1] = make_int2((yi0 * W + xi1) * 256, __float_as_int(w01));
    tiw[e][2] = make_int2((yi1 * W + xi0) * 256, __float_as_int(w10));
    tiw[e][3] = make_int2((yi1 * W + xi1) * 256, __float_as_int(w11));
  }
  __syncthreads();

  const char* fb = (const char*)fcl + (size_t)b * HW * 256;
  int c2 = lane & 31;          /* channel pair: channels 2c2, 2c2+1 */
  int c28 = c2 * 8;
  int half = lane >> 5;        /* which of the 2 positions this lane samples */
  int parow = qq * 16 + half;  /* pa = parow + pp*2 */

  float2 sv[8][4];             /* sampled values ring (in flight) */
  float  sw[8][4];             /* their bilinear weights */
  f32x4 acc[4];
#pragma unroll
  for (int nt = 0; nt < 4; nt++) acc[nt] = (f32x4){0.f, 0.f, 0.f, 0.f};

  auto issue = [&](int ks, int pp) {
    int e = ks * 64 + parow + pp * 2;
    int4 q0 = *(const int4*)&tiw[e][0];
    int4 q1 = *(const int4*)&tiw[e][2];
    sv[pp][0] = *(const float2*)(fb + (q0.x + c28)); sw[pp][0] = __int_as_float(q0.y);
    sv[pp][1] = *(const float2*)(fb + (q0.z + c28)); sw[pp][1] = __int_as_float(q0.w);
    sv[pp][2] = *(const float2*)(fb + (q1.x + c28)); sw[pp][2] = __int_as_float(q1.y);
    sv[pp][3] = *(const float2*)(fb + (q1.z + c28)); sw[pp][3] = __int_as_float(q1.w);
  };
  auto consume = [&](int pp, int bi) {
    int pa = parow + pp * 2;
    float slo = sw[pp][0] * sv[pp][0].x + sw[pp][1] * sv[pp][1].x +
                sw[pp][2] * sv[pp][2].x + sw[pp][3] * sv[pp][3].x;
    float shi = sw[pp][0] * sv[pp][0].y + sw[pp][1] * sv[pp][1].y +
                sw[pp][2] * sv[pp][2].y + sw[pp][3] * sv[pp][3].y;
    ((unsigned*)sAb[bi])[pa * 36 + c2] = pack2(slo, shi);
  };
  auto mfmastep = [&](int ks, int bi) {
#pragma unroll
    for (int ch = 0; ch < 2; ch++) {
      bf16x8 af = *(const bf16x8*)&sAb[bi][mrow * 72 + ch * 32 + quad * 8];
      int kc = ks * 2 + ch;
#pragma unroll
      for (int nt = 0; nt < 4; nt++) {
        bf16x8 bf = ((const bf16x8*)wdb3)[(kc * 4 + nt) * 64 + lane];
        acc[nt] = __builtin_amdgcn_mfma_f32_16x16x32_bf16(af, bf, acc[nt], 0, 0, 0);
      }
    }
  };

  /* prologue: fill the ring with ks=0 */
#pragma unroll
  for (int pp = 0; pp < 8; pp++) issue(0, pp);
  /* steady state */
  for (int ks = 0; ks < 8; ks++) {
    int bi = ks & 1;
#pragma unroll
    for (int pp = 0; pp < 8; pp++) {
      consume(pp, bi);
      issue(ks + 1, pp);
    }
    mfmastep(ks, bi);
  }
  /* drain: ks = 8 */
#pragma unroll
  for (int pp = 0; pp < 8; pp++) consume(pp, 0);
  mfmastep(8, 0);

  __syncthreads();
  /* epilogue: bias + BN, bf16 stage to LDS (wave-private rows), write vcl bf16 */
#pragma unroll
  for (int nt = 0; nt < 4; nt++) {
    int o = nt * 16 + l15;
    float sc = bns[o], sb = bnb[o], bb = bd[o];
#pragma unroll
    for (int reg = 0; reg < 4; reg++) {
      int m = qq * 16 + quad * 4 + reg;
      sAb[0][m * 72 + o] = f2bf((acc[nt][reg] + bb) * sc + sb);
    }
  }
  __syncthreads();
  for (int rr = t; rr < 2048; rr += 256) {
    int p = rr >> 5, cc = rr & 31;
    ((unsigned*)vclb)[(size_t)(gpos0 + p) * 32 + cc] = ((const unsigned*)sAb[0])[p * 36 + cc];
  }
}

/* k4: pwconv2 via MFMA (M=64 pos, N=256 o, K=64) + sigmoid gate.
   A-frags loaded directly from bf16 vcl (no LDS staging, no cvt). */
__global__ __launch_bounds__(256) void k4_pw2(
    const float* __restrict__ x, const short* __restrict__ vclb,
    const short* __restrict__ wdb2, const float* __restrict__ b2,
    float* __restrict__ out) {
  __shared__ float sA[64 * 66];
  int t = threadIdx.x;
  int lane = t & 63;
  int qq = __builtin_amdgcn_readfirstlane(t >> 6);
  int quad = lane >> 4, l15 = lane & 15;
  int mrow = qq * 16 + l15;
  int gpos0 = xswiz(blockIdx.x) * 64;
  int b = gpos0 / HW, hw0 = gpos0 - b * HW;

  const bf16x8* ap = (const bf16x8*)(vclb + (size_t)(gpos0 + mrow) * 64);
  bf16x8 af0 = ap[quad];
  bf16x8 af1 = ap[4 + quad];

  f32x4 acc[16];
#pragma unroll
  for (int nt = 0; nt < 16; nt++) acc[nt] = (f32x4){0.f, 0.f, 0.f, 0.f};
#pragma unroll
  for (int nt = 0; nt < 16; nt++) {
    bf16x8 bf0 = ((const bf16x8*)wdb2)[(0 * 16 + nt) * 64 + lane];
    bf16x8 bf1 = ((const bf16x8*)wdb2)[(1 * 16 + nt) * 64 + lane];
    acc[nt] = __builtin_amdgcn_mfma_f32_16x16x32_bf16(af0, bf0, acc[nt], 0, 0, 0);
    acc[nt] = __builtin_amdgcn_mfma_f32_16x16x32_bf16(af1, bf1, acc[nt], 0, 0, 0);
  }
  /* epilogue in 4 chunks of 64 out-channels through LDS */
  for (int nc = 0; nc < 4; nc++) {
    __syncthreads();
#pragma unroll
    for (int nt2 = 0; nt2 < 4; nt2++) {
      int nt = nc * 4 + nt2;
      int o1 = nt2 * 16 + l15;
#pragma unroll
      for (int reg = 0; reg < 4; reg++) {
        int m = qq * 16 + quad * 4 + reg;
        sA[m * 66 + o1] = acc[nt][reg] + b2[nc * 64 + nt2 * 16 + l15];
      }
    }
    __syncthreads();
    for (int rr = t; rr < 4096; rr += 256) {
      int o1 = rr >> 6, p = rr & 63;
      int o = nc * 64 + o1;
      float wv = sA[p * 66 + o1];
      float sg = 1.f / (1.f + __expf(-wv));
      size_t gi = ((size_t)b * CIN + o) * HW + hw0 + p;
      out[gi] = x[gi] * sg;
    }
  }
}

extern "C" void kernel_launch(void* const* d_in, const int* in_sizes, int n_in,
                              void* d_out, int out_size, void* d_ws, size_t ws_size,
                              hipStream_t stream) {
  const float* x     = (const float*)d_in[0];
  const float* w1    = (const float*)d_in[1];
  const float* b1    = (const float*)d_in[2];
  const float* woff  = (const float*)d_in[3];
  const float* boff  = (const float*)d_in[4];
  const float* wd    = (const float*)d_in[5];
  const float* bd    = (const float*)d_in[6];
  const float* gamma = (const float*)d_in[7];
  const float* beta  = (const float*)d_in[8];
  const float* rmean = (const float*)d_in[9];
  const float* rvar  = (const float*)d_in[10];
  const float* w2    = (const float*)d_in[11];
  const float* b2    = (const float*)d_in[12];
  float* out = (float*)d_out;
  float* ws  = (float*)d_ws;

  dim3 blk(256);
  k0_prep<<<dim3(345), blk, 0, stream>>>(w1, woff, wd, w2, gamma, beta, rmean, rvar, ws);
  k1_pw1<<<dim3(NBLK), blk, 0, stream>>>(x, (const short*)(ws + OFF_WDB1), b1, ws + OFF_FCL);
  k2_off<<<dim3(NBLK), blk, 0, stream>>>(ws + OFF_FCL, (const short*)(ws + OFF_WDBO),
                                         boff, ws + OFF_OFFS);
  k3_deform<<<dim3(NBLK), blk, 0, stream>>>(ws + OFF_FCL, ws + OFF_OFFS,
                                            (const short*)(ws + OFF_WDB3), bd,
                                            ws + OFF_BNS, ws + OFF_BNB,
                                            (short*)(ws + OFF_VCL));
  k4_pw2<<<dim3(NBLK), blk, 0, stream>>>(x, (const short*)(ws + OFF_VCL),
                                         (const short*)(ws + OFF_WDB2), b2, out);
}